// Round 8
// baseline (187.489 us; speedup 1.0000x reference)
//
#include <hip/hip_runtime.h>

#define BATCH 128
#define VIS   98
#define TOK   196
#define TOK2  392
#define ENC   1024
#define DEC   512
#define MSK   294   // 2*TOK - VIS

#define NWB 256    // (DEC*ENC/4) float4s / 512 threads
#define NFILL 1176 // 37632 masked tokens / 32 per block
#define NGEMM 196  // one block per 64-row m-panel, full N=512

typedef __bf16 bf16x8 __attribute__((ext_vector_type(8)));
typedef float  f32x4  __attribute__((ext_vector_type(4)));

__device__ __forceinline__ unsigned short f2bf(float f) {
    union { float f; unsigned u; } c; c.f = f;
    unsigned u = c.u;
    return (unsigned short)((u + 0x7fffu + ((u >> 16) & 1u)) >> 16);
}

// async global -> LDS, 16 B per lane; LDS dest must be wave-uniform base + lane*16
__device__ __forceinline__ void g2lds16(const void* gptr, void* lptr) {
    __builtin_amdgcn_global_load_lds(
        (const __attribute__((address_space(1))) void*)gptr,
        (__attribute__((address_space(3))) void*)lptr, 16, 0, 0);
}

// Launch 1 — W convert + visibility maps + masked fill (all independent, BW-bound):
//   blocks [0, NWB)        : W fp32 -> bf16
//   blocks [NWB, +BATCH)   : visibility map per batch row
//   blocks [NWB+BATCH, +NFILL): masked fill DIRECT FROM mids (no vis dependency).
__global__ __launch_bounds__(512) void setup_fill(
    const float* __restrict__ W,
    const int* __restrict__ mids,
    const float* __restrict__ mask_token,
    const float* __restrict__ pos,
    const float* __restrict__ ve,
    unsigned short* __restrict__ wbm,
    int* __restrict__ visids,
    float* __restrict__ out) {
    int bid = blockIdx.x, tid = threadIdx.x;
    if (bid < NWB) {
        int i = bid * 512 + tid;
        float4 f = ((const float4*)W)[i];
        ushort4 o;
        o.x = f2bf(f.x); o.y = f2bf(f.y); o.z = f2bf(f.z); o.w = f2bf(f.w);
        ((ushort4*)wbm)[i] = o;
        return;
    }
    if (bid < NWB + BATCH) {
        // ---- visibility map ----
        int b = bid - NWB;
        __shared__ unsigned char lf[TOK2];
        __shared__ int wtot[8];
        if (tid < TOK2) lf[tid] = 1;
        __syncthreads();
        if (tid < MSK) lf[mids[b * MSK + tid]] = 0;
        __syncthreads();
        int flag = (tid < TOK2) ? (int)lf[tid] : 0;
        unsigned long long bal = __ballot(flag != 0);
        int lane = tid & 63, wv = tid >> 6;
        int pre = __popcll(bal & ((1ull << lane) - 1ull));
        if (lane == 0) wtot[wv] = __popcll(bal);
        __syncthreads();
        int off = 0;
        for (int i = 0; i < wv; ++i) off += wtot[i];
        if (flag) visids[b * VIS + off + pre] = tid;   // stable: ascending token id
        return;
    }
    // ---- masked fill from mids: 32 tokens per block ----
    int fb = bid - (NWB + BATCH);
    __shared__ int base[32];   // out float4 base per token
    __shared__ int tsl[32];    // token id within [0, 2T) per token
    if (tid < 32) {
        int fid = fb * 32 + tid;          // fid = b*MSK + m (row-major)
        int b = fid / MSK;
        int t = mids[fid];
        tsl[tid] = t;
        base[tid] = (b * TOK2 + t) * 128;
    }
    __syncthreads();
    float4 m = ((const float4*)mask_token)[tid & 127];
    #pragma unroll
    for (int i = 0; i < 8; ++i) {
        int g = i * 512 + tid;
        int ltok = g >> 7;
        int d4 = tid & 127;
        int t = tsl[ltok];
        float4 p = ((const float4*)pos)[t * 128 + d4];
        float4 v = ((const float4*)(ve + (t >= TOK ? DEC : 0)))[d4];
        float4 r;
        r.x = m.x + p.x + v.x;
        r.y = m.y + p.y + v.y;
        r.z = m.z + p.z + v.z;
        r.w = m.w + p.w + v.w;
        ((float4*)out)[base[ltok] + d4] = r;
    }
}

// Convert one 64x512 fp32 half-panel of x into swizzled bf16 LDS.
// thread t: row cr = t>>3, chunk sub cj = t&7; handles logical chunks c = cj+8*kk.
// Store chunk c of row r at slot c ^ (r&7) (matches fragment read: l16&7 == row&7).
__device__ __forceinline__ void convertA(const float* __restrict__ gx,
                                         unsigned short* __restrict__ As,
                                         int tid, int h) {
    int cr = tid >> 3, cj = tid & 7;
    const float* src = gx + (size_t)cr * ENC + h * 512;
    float4 f[16];
    #pragma unroll
    for (int kk = 0; kk < 8; ++kk) {
        const float4* p = (const float4*)(src + (cj + 8 * kk) * 8);
        f[2 * kk]     = p[0];
        f[2 * kk + 1] = p[1];
    }
    #pragma unroll
    for (int kk = 0; kk < 8; ++kk) {
        int c = cj + 8 * kk;
        bf16x8 v;
        v[0] = (__bf16)f[2*kk].x;   v[1] = (__bf16)f[2*kk].y;
        v[2] = (__bf16)f[2*kk].z;   v[3] = (__bf16)f[2*kk].w;
        v[4] = (__bf16)f[2*kk+1].x; v[5] = (__bf16)f[2*kk+1].y;
        v[6] = (__bf16)f[2*kk+1].z; v[7] = (__bf16)f[2*kk+1].w;
        *(bf16x8*)((char*)As + cr * 1024 + ((c ^ (cr & 7)) * 16)) = v;
    }
}

// Launch 2 — self-converting GEMM: one block per 64-row m-panel, FULL N=512.
// 512 thr = 8 waves (2m x 4n); wave tile 32m x 128n; acc[2][8]; BK=32, 32 k-steps.
// A: block converts its own x panel fp32->bf16 into LDS, one 64x512 half at a
//    time (k-halves at s=0 and s=16). Cold-x latency paid ONCE per half in a
//    deep 16-loads/thread burst (BW-bound) — NOT per K-step (r2-r5's mistake).
//    No xb round-trip (saves 51.4 MB HBM) and no convert->gemm launch dependency.
// B: wbm bf16 via global_load_lds, double-buffered 32 KB tiles, counted
//    vmcnt(4) + raw s_barrier (r4-verified sync skeleton). W is 1 MB -> L2-hot.
// LDS: As 64 KB + Bs 2x32 KB = 128.5 KB (gfx950 allows; m201 uses 128 KB).
// A swizzle: chunk c of row r at slot c^(r&7); read slot (sl*4+q)^(l16&7).
// B swizzle: chunk q of col at slot q^((col>>1)&3)  [2-way bank access = free];
//    staged via pre-swizzled global src: issue qq, thread t -> col qq*128+(t>>2),
//    slot t&3, logical chunk (t&3)^((t>>3)&3).
// mfma_f32_16x16x32_bf16: A lane: row=l&15, k=(l>>4)*8+j ; B lane: col=l&15,
//    same k; D lane: col=l&15, row=(l>>4)*4+reg   [m89-verified layout]
__global__ __launch_bounds__(512, 2) void gemm_conv(
    const float* __restrict__ x,             // (B*V, ENC) fp32
    const unsigned short* __restrict__ wb,   // (DEC, ENC) bf16 bits
    const float* __restrict__ bias,
    const float* __restrict__ pos,
    const float* __restrict__ ve,
    const int* __restrict__ vis,             // (B*V) -> t
    float* __restrict__ out) {
    __shared__ unsigned short As[64 * 512];      // 64 KB (one K-half, bf16)
    __shared__ unsigned short Bs[2][512 * 32];   // 2 x 32 KB
    __shared__ int rowdst[64];
    __shared__ int rowt[64];

    int bid = blockIdx.x, tid = threadIdx.x;
    int lane = tid & 63, w = tid >> 6;
    int l16 = lane & 15, q = lane >> 4;
    int wm = w & 1, wn = w >> 1;
    int m0 = bid * 64;

    if (tid < 64) {
        int gr = m0 + tid;
        int t = vis[gr];
        rowt[tid] = t;
        rowdst[tid] = (gr / VIS) * TOK2 + t;
    }

    // B staging base: col part (t>>2), pre-swizzled chunk (t&3)^((t>>3)&3)
    const unsigned short* gBbase = wb + (size_t)(tid >> 2) * ENC
                                      + (((tid & 3) ^ ((tid >> 3) & 3)) * 8);
    const float* gx = x + (size_t)m0 * ENC;

    f32x4 acc[2][8];
    #pragma unroll
    for (int i = 0; i < 2; ++i)
        #pragma unroll
        for (int j = 0; j < 8; ++j)
            acc[i][j] = (f32x4){0.f, 0.f, 0.f, 0.f};

    // prologue: stage B step 0 into buf 0 (oldest in vmcnt queue), then convert
    // half 0 (its reg-loads are consumed -> compiler drains them AND B0 is older).
    #pragma unroll
    for (int qq = 0; qq < 4; ++qq)
        g2lds16(gBbase + (size_t)qq * 128 * ENC,
                (char*)(&Bs[0][0]) + qq * 8192 + tid * 16);
    convertA(gx, As, tid, 0);
    __syncthreads();    // full drain: B0 + convert ds_writes + rowt/rowdst

    for (int s = 0; s < 32; ++s) {
        int buf = s & 1;
        if (s < 31) {
            int k0 = (s + 1) * 32;
            #pragma unroll
            for (int qq = 0; qq < 4; ++qq)
                g2lds16(gBbase + (size_t)qq * 128 * ENC + k0,
                        (char*)(&Bs[buf ^ 1][0]) + qq * 8192 + tid * 16);
            __builtin_amdgcn_sched_barrier(0);
            asm volatile("s_waitcnt vmcnt(4)" ::: "memory");  // B(s) done; B(s+1) in flight
        } else {
            __builtin_amdgcn_sched_barrier(0);
            asm volatile("s_waitcnt vmcnt(0)" ::: "memory");
        }
        __builtin_amdgcn_s_barrier();
        __builtin_amdgcn_sched_barrier(0);

        int sl = s & 15;
        const char* Bb = (const char*)(&Bs[buf][0]);
        bf16x8 afrag[2], bfrag[8];
        #pragma unroll
        for (int i = 0; i < 2; ++i) {
            int row = wm * 32 + i * 16 + l16;
            afrag[i] = *(const bf16x8*)((const char*)As + row * 1024
                        + (((sl * 4 + q) ^ (l16 & 7)) * 16));
        }
        #pragma unroll
        for (int j = 0; j < 8; ++j) {
            int col = wn * 128 + j * 16 + l16;
            bfrag[j] = *(const bf16x8*)(Bb + col * 64
                        + ((q ^ ((col >> 1) & 3)) * 16));
        }
        #pragma unroll
        for (int i = 0; i < 2; ++i)
            #pragma unroll
            for (int j = 0; j < 8; ++j)
                acc[i][j] = __builtin_amdgcn_mfma_f32_16x16x32_bf16(afrag[i], bfrag[j], acc[i][j], 0, 0, 0);
        __builtin_amdgcn_s_barrier();   // all reads of Bs[buf]/As done before overwrite

        if (s == 15) {
            convertA(gx, As, tid, 1);   // overwrite As with K-half 1
            __syncthreads();            // drain converts before half-1 reads
        }
    }

    // epilogue: +bias +pos +view_embed, scatter rows to out[b, t, :]
    #pragma unroll
    for (int j = 0; j < 8; ++j) {
        int gcol = wn * 128 + j * 16 + l16;
        float bc = bias[gcol];
        float v0 = ve[gcol];
        float v1 = ve[DEC + gcol];
        #pragma unroll
        for (int i = 0; i < 2; ++i) {
            #pragma unroll
            for (int r = 0; r < 4; ++r) {
                int rl = wm * 32 + i * 16 + q * 4 + r;
                int t = rowt[rl];
                float val = acc[i][j][r] + bc + pos[(size_t)t * DEC + gcol]
                          + (t >= TOK ? v1 : v0);
                out[(size_t)rowdst[rl] * DEC + gcol] = val;
            }
        }
    }
}

extern "C" void kernel_launch(void* const* d_in, const int* in_sizes, int n_in,
                              void* d_out, int out_size, void* d_ws, size_t ws_size,
                              hipStream_t stream) {
    (void)in_sizes; (void)n_in; (void)out_size; (void)ws_size;
    const float* x    = (const float*)d_in[0];
    const int*   mids = (const int*)d_in[1];
    const float* W    = (const float*)d_in[2];
    const float* bias = (const float*)d_in[3];
    const float* mt   = (const float*)d_in[4];
    const float* pos  = (const float*)d_in[5];
    const float* ve   = (const float*)d_in[6];
    float* out = (float*)d_out;

    // workspace: W bf16 (1 MB) + visids
    unsigned short* wbm = (unsigned short*)d_ws;                     // DEC*ENC bf16
    int* visids = (int*)(wbm + (size_t)DEC * ENC);                   // B*V int

    hipLaunchKernelGGL(setup_fill, dim3(NWB + BATCH + NFILL), dim3(512), 0, stream,
                       W, mids, mt, pos, ve, wbm, visids, out);
    hipLaunchKernelGGL(gemm_conv, dim3(NGEMM), dim3(512), 0, stream,
                       x, wbm, bias, pos, ve, visids, out);
}

// Round 9
// 181.631 us; speedup vs baseline: 1.0323x; 1.0323x over previous
//
#include <hip/hip_runtime.h>

#define BATCH 128
#define VIS   98
#define TOK   196
#define TOK2  392
#define ENC   1024
#define DEC   512
#define MSK   294   // 2*TOK - VIS

#define NXB 1568   // x-convert blocks: (B*V*ENC/4) float4s / (512 thr * 4 per thread)
#define NWB 256    // (DEC*ENC/4) float4s / 512 threads
#define NFILL 1176 // 37632 masked tokens / 32 per block

#define NGEMM 784  // 4 n-blocks x 196 m-blocks

typedef __bf16 bf16x8 __attribute__((ext_vector_type(8)));
typedef float  f32x4  __attribute__((ext_vector_type(4)));

__device__ __forceinline__ unsigned short f2bf(float f) {
    union { float f; unsigned u; } c; c.f = f;
    unsigned u = c.u;
    return (unsigned short)((u + 0x7fffu + ((u >> 16) & 1u)) >> 16);
}

// async global -> LDS, 16 B per lane; LDS dest must be wave-uniform base + lane*16
__device__ __forceinline__ void g2lds16(const void* gptr, void* lptr) {
    __builtin_amdgcn_global_load_lds(
        (const __attribute__((address_space(1))) void*)gptr,
        (__attribute__((address_space(3))) void*)lptr, 16, 0, 0);
}

// Launch 1 — everything except the GEMM, all mutually independent, BW-bound.
// The xb round-trip is a WIN, not waste: it converts the GEMM's A-read from
// cold-HBM fp32 (~900cy, unhideable; r2/r3/r4/r8 all 60-80us) to L2/L3-warm
// bf16 (r1/r7 gemm ~20us). TLP (3-4 blocks/CU, simple syncthreads loop) is what
// hides latency on this machine; 1-block/CU schemes die (r8). Do not remove.
//   blocks [0, NXB)               : x fp32 -> bf16, 4 float4s/thread
//   blocks [NXB, +NWB)            : W fp32 -> bf16
//   blocks [NXB+NWB, +BATCH)      : visibility map per batch row
//   blocks [NXB+NWB+BATCH, +NFILL): masked fill DIRECT FROM mids (no vis dep)
__global__ __launch_bounds__(512) void setup_fill(
    const float* __restrict__ x,
    const float* __restrict__ W,
    const int* __restrict__ mids,
    const float* __restrict__ mask_token,
    const float* __restrict__ pos,
    const float* __restrict__ ve,
    unsigned short* __restrict__ xb,
    unsigned short* __restrict__ wbm,
    int* __restrict__ visids,
    float* __restrict__ out) {
    int bid = blockIdx.x, tid = threadIdx.x;
    if (bid < NXB) {
        // x convert: 4 strided float4s per thread (coalesced per instruction)
        int base = bid * 2048 + tid;
        #pragma unroll
        for (int k = 0; k < 4; ++k) {
            int i = base + k * 512;
            float4 f = ((const float4*)x)[i];
            ushort4 o;
            o.x = f2bf(f.x); o.y = f2bf(f.y); o.z = f2bf(f.z); o.w = f2bf(f.w);
            ((ushort4*)xb)[i] = o;
        }
        return;
    }
    if (bid < NXB + NWB) {
        int i = (bid - NXB) * 512 + tid;
        float4 f = ((const float4*)W)[i];
        ushort4 o;
        o.x = f2bf(f.x); o.y = f2bf(f.y); o.z = f2bf(f.z); o.w = f2bf(f.w);
        ((ushort4*)wbm)[i] = o;
        return;
    }
    if (bid < NXB + NWB + BATCH) {
        // ---- visibility map ----
        int b = bid - NXB - NWB;
        __shared__ unsigned char lf[TOK2];
        __shared__ int wtot[8];
        if (tid < TOK2) lf[tid] = 1;
        __syncthreads();
        if (tid < MSK) lf[mids[b * MSK + tid]] = 0;
        __syncthreads();
        int flag = (tid < TOK2) ? (int)lf[tid] : 0;
        unsigned long long bal = __ballot(flag != 0);
        int lane = tid & 63, wv = tid >> 6;
        int pre = __popcll(bal & ((1ull << lane) - 1ull));
        if (lane == 0) wtot[wv] = __popcll(bal);
        __syncthreads();
        int off = 0;
        for (int i = 0; i < wv; ++i) off += wtot[i];
        if (flag) visids[b * VIS + off + pre] = tid;   // stable: ascending token id
        return;
    }
    // ---- masked fill from mids: 32 tokens per block ----
    int fb = bid - (NXB + NWB + BATCH);
    __shared__ int base[32];   // out float4 base per token
    __shared__ int tsl[32];    // token id within [0, 2T) per token
    if (tid < 32) {
        int fid = fb * 32 + tid;          // fid = b*MSK + m (row-major)
        int b = fid / MSK;
        int t = mids[fid];
        tsl[tid] = t;
        base[tid] = (b * TOK2 + t) * 128;
    }
    __syncthreads();
    float4 m = ((const float4*)mask_token)[tid & 127];
    #pragma unroll
    for (int i = 0; i < 8; ++i) {
        int g = i * 512 + tid;
        int ltok = g >> 7;
        int d4 = tid & 127;
        int t = tsl[ltok];
        float4 p = ((const float4*)pos)[t * 128 + d4];
        float4 v = ((const float4*)(ve + (t >= TOK ? DEC : 0)))[d4];
        float4 r;
        r.x = m.x + p.x + v.x;
        r.y = m.y + p.y + v.y;
        r.z = m.z + p.z + v.z;
        r.w = m.w + p.w + v.w;
        ((float4*)out)[base[ltok] + d4] = r;
    }
}

// Launch 2 — pure GEMM: xp = x @ W^T + bias, scattered to out[b, visids[b,v], :]
//   (+pos +view_embed). 64m x 128n tile, BK=64, 256 thr (4 waves 2x2; wave =
//   32m x 64n, acc[2][4]). r1 core: both operands bf16 via global_load_lds,
//   single-buffered, __syncthreads — TLP at 3-4 blocks/CU does the latency
//   hiding (r4/r5/r8 dbuf/vmcnt/fused experiments all slower; don't re-add).
// XCD co-location: 4 n-blocks of each m-block share bid%8 -> same XCD L2
//   (r4: FETCH 110->39 MB); per-XCD xb slice ~3.2 MB fits 4 MB L2.
// XOR chunk swizzle: row r stores logical chunk c at slot c ^ (r&7); fragment
//   read of chunk (u*4+q) reads slot (u*4+q)^(l16&7). Bank conflicts: 0 (r1-r7).
// mfma_f32_16x16x32_bf16: A lane: row=l&15, k=(l>>4)*8+j ; B lane: col=l&15,
//   same k; D lane: col=l&15, row=(l>>4)*4+reg   [m89-verified layout]
__global__ __launch_bounds__(256, 4) void gemm_scatter(
    const unsigned short* __restrict__ xb,   // (B*V, ENC) bf16 bits
    const unsigned short* __restrict__ wb,   // (DEC, ENC) bf16 bits
    const float* __restrict__ bias,
    const float* __restrict__ pos,
    const float* __restrict__ ve,
    const int* __restrict__ vis,             // (B*V) -> t
    float* __restrict__ out) {
    __shared__ unsigned short As[64 * 64];   // 8 KB
    __shared__ unsigned short Bs[128 * 64];  // 16 KB
    __shared__ int rowdst[64];
    __shared__ int rowt[64];

    int bid = blockIdx.x;
    int tid = threadIdx.x;
    int lane = tid & 63, w = tid >> 6;
    int l16 = lane & 15, q = lane >> 4;
    int wm = w & 1, wn = w >> 1;

    // XCD co-location: for bid<768, mb = (bid&7) + 8*(bid>>5), nb = (bid>>3)&3
    //   -> all 4 n-blocks of an m-block share bid%8 (same XCD). Tail: plain map.
    int mb, nb;
    if (bid < 768) { mb = (bid & 7) + ((bid >> 5) << 3); nb = (bid >> 3) & 3; }
    else           { int ii = bid - 768; mb = 192 + (ii & 3); nb = ii >> 2; }
    int m0 = mb * 64, n0 = nb * 128;

    if (tid < 64) {
        int gr = m0 + tid;
        int t = vis[gr];
        rowt[tid] = t;
        rowdst[tid] = (gr / VIS) * TOK2 + t;
    }

    // staging: thread -> row (tid>>3), chunk slot (tid&7); global chunk c = slot ^ (row&7)
    int c = (tid & 7) ^ ((tid >> 3) & 7);
    const unsigned short* gA = xb + (size_t)(m0 + (tid >> 3)) * ENC + c * 8;
    const unsigned short* gB = wb + (size_t)(n0 + (tid >> 3)) * ENC + c * 8;
    char* ldsA = (char*)As + tid * 16;
    char* ldsB = (char*)Bs + tid * 16;

    f32x4 acc[2][4];
    #pragma unroll
    for (int i = 0; i < 2; ++i)
        #pragma unroll
        for (int j = 0; j < 4; ++j)
            acc[i][j] = (f32x4){0.f, 0.f, 0.f, 0.f};

    for (int k0 = 0; k0 < ENC; k0 += 64) {
        __syncthreads();
        #pragma unroll
        for (int t = 0; t < 2; ++t)                  // A tile: 64 rows x 64 k bf16
            g2lds16(gA + (size_t)t * 32 * ENC + k0, ldsA + t * 4096);
        #pragma unroll
        for (int t = 0; t < 4; ++t)                  // B tile: 128 rows x 64 k bf16
            g2lds16(gB + (size_t)t * 32 * ENC + k0, ldsB + t * 4096);
        __syncthreads();

        #pragma unroll
        for (int u = 0; u < 2; ++u) {                // two k32 substeps
            int slot = ((u * 4 + q) ^ (l16 & 7)) * 16;
            bf16x8 bfrag[4], afrag[2];
            #pragma unroll
            for (int j = 0; j < 4; ++j)
                bfrag[j] = *(const bf16x8*)((const char*)Bs + (wn * 64 + j * 16 + l16) * 128 + slot);
            #pragma unroll
            for (int i = 0; i < 2; ++i)
                afrag[i] = *(const bf16x8*)((const char*)As + (wm * 32 + i * 16 + l16) * 128 + slot);
            #pragma unroll
            for (int i = 0; i < 2; ++i)
                #pragma unroll
                for (int j = 0; j < 4; ++j)
                    acc[i][j] = __builtin_amdgcn_mfma_f32_16x16x32_bf16(afrag[i], bfrag[j], acc[i][j], 0, 0, 0);
        }
    }

    // epilogue: +bias +pos +view_embed, scatter rows to out[b, t, :]
    #pragma unroll
    for (int j = 0; j < 4; ++j) {
        int gcol = n0 + wn * 64 + j * 16 + l16;
        float bc = bias[gcol];
        float v0 = ve[gcol];
        float v1 = ve[DEC + gcol];
        #pragma unroll
        for (int i = 0; i < 2; ++i) {
            #pragma unroll
            for (int r = 0; r < 4; ++r) {
                int rl = wm * 32 + i * 16 + q * 4 + r;
                int t = rowt[rl];
                float val = acc[i][j][r] + bc + pos[(size_t)t * DEC + gcol]
                          + (t >= TOK ? v1 : v0);
                out[(size_t)rowdst[rl] * DEC + gcol] = val;
            }
        }
    }
}

extern "C" void kernel_launch(void* const* d_in, const int* in_sizes, int n_in,
                              void* d_out, int out_size, void* d_ws, size_t ws_size,
                              hipStream_t stream) {
    (void)in_sizes; (void)n_in; (void)out_size; (void)ws_size;
    const float* x    = (const float*)d_in[0];
    const int*   mids = (const int*)d_in[1];
    const float* W    = (const float*)d_in[2];
    const float* bias = (const float*)d_in[3];
    const float* mt   = (const float*)d_in[4];
    const float* pos  = (const float*)d_in[5];
    const float* ve   = (const float*)d_in[6];
    float* out = (float*)d_out;

    // workspace: x bf16 (25.7 MB) + W bf16 (1 MB) + visids
    unsigned short* xb = (unsigned short*)d_ws;                      // B*V*ENC bf16
    unsigned short* wbm = xb + (size_t)BATCH * VIS * ENC;            // DEC*ENC bf16
    int* visids = (int*)(wbm + (size_t)DEC * ENC);                   // B*V int

    hipLaunchKernelGGL(setup_fill, dim3(NXB + NWB + BATCH + NFILL), dim3(512), 0, stream,
                       x, W, mids, mt, pos, ve, xb, wbm, visids, out);
    hipLaunchKernelGGL(gemm_scatter, dim3(NGEMM), dim3(256), 0, stream,
                       xb, wbm, bias, pos, ve, visids, out);
}